// Round 1
// baseline (191.233 us; speedup 1.0000x reference)
//
#include <hip/hip_runtime.h>
#include <hip/hip_bf16.h>

// Problem constants (fixed by setup_inputs)
#define B   8
#define T   2048
#define C   256      // channels; 64 float4
#define L   32       // query rows / label count
#define DQ  512
#define NW  2017     // T - window_size + 1
#define NK  8        // num_chunks
#define CIC 4        // window/num_chunks
#define WT  32       // w-tile per block
#define SROWS (WT + (NK-1)*CIC)   // 60 pooled rows per tile
#define LROWS (SROWS + 3)         // 63 label rows per tile (w0 .. w0+62)

typedef float nfloat4 __attribute__((ext_vector_type(4)));  // native vec for nt-store

// ---------------- Kernel 1: enc1/enc2 = query @ W{1,2} + b{1,2} ----------------
// (unchanged from previous best)
__global__ __launch_bounds__(256) void enc_kernel(
    const float* __restrict__ query, const float* __restrict__ W1,
    const float* __restrict__ b1, const float* __restrict__ W2,
    const float* __restrict__ b2, float* __restrict__ enc1,
    float* __restrict__ enc2) {
  const int lg = blockIdx.x, b = blockIdx.y, cs = blockIdx.z;
  const int tid = threadIdx.x;
  const int tx = tid & 63;    // channel within 64-slice
  const int dq = tid >> 6;    // d-quarter (wave-uniform)
  const int c = cs * 64 + tx;
  __shared__ float4 qs4[4][DQ / 4];        // [j][g] 8 KB
  __shared__ float red[2][4][4][64];       // [e][dq][j][tx] 8 KB

  const float4* q4 = (const float4*)(query + ((size_t)b * L + lg * 4) * DQ);
  for (int i = tid; i < 4 * (DQ / 4); i += 256) {
    const int j = i >> 7, g = i & 127;
    qs4[j][g] = q4[j * (DQ / 4) + g];
  }
  __syncthreads();

  float a1[4] = {0.f, 0.f, 0.f, 0.f};
  float a2[4] = {0.f, 0.f, 0.f, 0.f};
  const int g0 = dq * 32;
#pragma unroll 4
  for (int gg = 0; gg < 32; ++gg) {
    const int g = g0 + gg;
    const float4 q0 = qs4[0][g], q1 = qs4[1][g], q2 = qs4[2][g], q3 = qs4[3][g];
    const float* wp1 = W1 + (size_t)(4 * g) * C + c;
    const float* wp2 = W2 + (size_t)(4 * g) * C + c;
    const float w10 = wp1[0], w11 = wp1[C], w12 = wp1[2 * C], w13 = wp1[3 * C];
    const float w20 = wp2[0], w21 = wp2[C], w22 = wp2[2 * C], w23 = wp2[3 * C];
    a1[0] = fmaf(q0.x, w10, fmaf(q0.y, w11, fmaf(q0.z, w12, fmaf(q0.w, w13, a1[0]))));
    a1[1] = fmaf(q1.x, w10, fmaf(q1.y, w11, fmaf(q1.z, w12, fmaf(q1.w, w13, a1[1]))));
    a1[2] = fmaf(q2.x, w10, fmaf(q2.y, w11, fmaf(q2.z, w12, fmaf(q2.w, w13, a1[2]))));
    a1[3] = fmaf(q3.x, w10, fmaf(q3.y, w11, fmaf(q3.z, w12, fmaf(q3.w, w13, a1[3]))));
    a2[0] = fmaf(q0.x, w20, fmaf(q0.y, w21, fmaf(q0.z, w22, fmaf(q0.w, w23, a2[0]))));
    a2[1] = fmaf(q1.x, w20, fmaf(q1.y, w21, fmaf(q1.z, w22, fmaf(q1.w, w23, a2[1]))));
    a2[2] = fmaf(q2.x, w20, fmaf(q2.y, w21, fmaf(q2.z, w22, fmaf(q2.w, w23, a2[2]))));
    a2[3] = fmaf(q3.x, w20, fmaf(q3.y, w21, fmaf(q3.z, w22, fmaf(q3.w, w23, a2[3]))));
  }
#pragma unroll
  for (int j = 0; j < 4; ++j) {
    red[0][dq][j][tx] = a1[j];
    red[1][dq][j][tx] = a2[j];
  }
  __syncthreads();

  for (int o = tid; o < 512; o += 256) {
    const int e = o >> 8, j = (o >> 6) & 3, t = o & 63;
    const float v = red[e][0][j][t] + red[e][1][j][t] +
                    red[e][2][j][t] + red[e][3][j][t];
    const int cc = cs * 64 + t;
    const size_t off = ((size_t)b * L + lg * 4 + j) * C + cc;
    if (e == 0) enc1[off] = v + b1[cc];
    else        enc2[off] = v + b2[cc];
  }
}

// ---------------- Kernel 2 (fused): labels + majority + pooling + modulated out ----
// Fuses the old label_kernel and out_kernel per 32-w tile. Labels for rows
// [w0, w0+62] are computed locally (2x redundancy at tile overlap, cheap VALU)
// so the store-bound phase of one block overlaps the label phase of others,
// vis is staged from HBM once, and the labels global round-trip disappears.
//
// LDS union (69.6 KB -> 2 blocks/CU):
//   label phase: raw[32][64] f4 (32 KB, staged in 2 row-chunks) + pacc[4][63][36]
//   pool phase:  S4[60][64] f4 (60 KB) reuses the same bytes.
// All float summation orders are bit-identical to the previous 3-kernel version.
__global__ __launch_bounds__(256) void fused_kernel(
    const float* __restrict__ vis, const float* __restrict__ enc1,
    const float* __restrict__ enc2, float* __restrict__ out) {
  const int b = blockIdx.y;
  const int w0 = blockIdx.x * WT;
  const int tid = threadIdx.x;
  const int lane = tid & 63;
  const int wv = tid >> 6;              // wave id, wave-uniform
  const int l = tid & 31;               // label row (label phase)
  const int part = tid >> 5;            // 8-way channel split (label phase)

  __shared__ alignas(16) char smem[69056];   // max(32768+36288, 61440)
  float4* raw = (float4*)smem;                                   // [32][64]
  float (*pacc)[LROWS][36] = (float (*)[LROWS][36])(smem + 32768); // [4][63][36]
  float4* S4 = (float4*)smem;                                    // [60][64], pool phase
  __shared__ int lbl[LROWS];
  __shared__ int slbl[SROWS];

  // enc1 fragment per thread (32 KB set, L2-hot)
  float4 ef[8];
  {
    const float4* e1p = (const float4*)(enc1 + ((size_t)b * L + l) * C) + part * 8;
#pragma unroll
    for (int j = 0; j < 8; ++j) ef[j] = e1p[j];
  }
  const float4* vb = (const float4*)(vis + (size_t)b * T * C);

  // ---- label phase: two row-chunks through the 32-row raw buffer ----
#pragma unroll 1
  for (int ch = 0; ch < 2; ++ch) {
    const int base = ch * 32;
    const int nrows = ch ? (LROWS - 32) : 32;   // 32 then 31
    if (ch) __syncthreads();   // all reads of previous chunk done before overwrite
    for (int i = tid; i < nrows * 64; i += 256) {
      int t = w0 + base + (i >> 6);
      t = t > (T - 1) ? (T - 1) : t;            // clamp; matches old LCL semantics
      raw[i] = vb[(size_t)t * 64 + (i & 63)];
    }
    __syncthreads();
    for (int t = 0; t < nrows; ++t) {
      const float4* vr = &raw[t * 64 + part * 8];
      float a = 0.f;
#pragma unroll
      for (int j = 0; j < 8; ++j) {
        const float4 v = vr[j];
        a = fmaf(v.x, ef[j].x, fmaf(v.y, ef[j].y, fmaf(v.z, ef[j].z, fmaf(v.w, ef[j].w, a))));
      }
      a += __shfl_down(a, 32);                    // part-pair sum (deterministic)
      if (!(tid & 32)) pacc[tid >> 6][base + t][l] = a;
    }
  }
  __syncthreads();

  // ---- final label reduce + argmax (identical order/tie-break to label_kernel) ----
  if (tid < LROWS) {
    float4 s4[8];
#pragma unroll
    for (int j = 0; j < 8; ++j) s4[j] = make_float4(0.f, 0.f, 0.f, 0.f);
#pragma unroll
    for (int p = 0; p < 4; ++p) {
      const float4* pp = (const float4*)pacc[p][tid];
#pragma unroll
      for (int j = 0; j < 8; ++j) {
        s4[j].x += pp[j].x; s4[j].y += pp[j].y;
        s4[j].z += pp[j].z; s4[j].w += pp[j].w;
      }
    }
    float bv = -INFINITY;
    int bi = 0;
#pragma unroll
    for (int j = 0; j < 8; ++j) {
      if (s4[j].x > bv) { bv = s4[j].x; bi = 4 * j; }
      if (s4[j].y > bv) { bv = s4[j].y; bi = 4 * j + 1; }
      if (s4[j].z > bv) { bv = s4[j].z; bi = 4 * j + 2; }
      if (s4[j].w > bv) { bv = s4[j].w; bi = 4 * j + 3; }
    }
    lbl[tid] = bi;
  }
  __syncthreads();   // lbl ready; all pacc reads done -> union region reusable

  // ---- register-stage vis rows (L1/L2-hot re-read) for pooling ----
  float4 r[18];
  {
    const int s0 = wv * (SROWS / 4);
#pragma unroll
    for (int j = 0; j < 18; ++j) {
      int t = w0 + s0 + j;
      t = t > (T - 1) ? (T - 1) : t;    // clamp; clamped rows never used
      r[j] = vb[(size_t)t * 64 + lane];
    }
  }

  // ---- majority vote (identical to old out_kernel, source now LDS lbl) ----
  if (tid < SROWS) {
    const int l0 = lbl[tid], l1 = lbl[tid + 1], l2 = lbl[tid + 2], l3 = lbl[tid + 3];
    const int c0 = 1 + (l0 == l1) + (l0 == l2) + (l0 == l3);
    const int c1 = 1 + (l1 == l0) + (l1 == l2) + (l1 == l3);
    const int c2 = 1 + (l2 == l0) + (l2 == l1) + (l2 == l3);
    const int c3 = 1 + (l3 == l0) + (l3 == l1) + (l3 == l2);
    int best = l0, bc = c0;
    if (c1 > bc || (c1 == bc && l1 < best)) { best = l1; bc = c1; }
    if (c2 > bc || (c2 == bc && l2 < best)) { best = l2; bc = c2; }
    if (c3 > bc || (c3 == bc && l3 < best)) { best = l3; bc = c3; }
    slbl[tid] = best;
  }

  // ---- pooled means into S4 (overwrites raw/pacc; safe: last read pre-barrier) ----
  {
    const int s0 = wv * (SROWS / 4);
#pragma unroll
    for (int s = 0; s < SROWS / 4; ++s) {
      float4 o;
      o.x = (r[s].x + r[s + 1].x + r[s + 2].x + r[s + 3].x) * 0.25f;
      o.y = (r[s].y + r[s + 1].y + r[s + 2].y + r[s + 3].y) * 0.25f;
      o.z = (r[s].z + r[s + 1].z + r[s + 2].z + r[s + 3].z) * 0.25f;
      o.w = (r[s].w + r[s + 1].w + r[s + 2].w + r[s + 3].w) * 0.25f;
      S4[(s0 + s) * 64 + lane] = o;
    }
  }
  __syncthreads();

  // ---- gather enc2 + modulate + nt-store (identical to old out_kernel) ----
  const float4* e2b = (const float4*)(enc2 + (size_t)b * L * C);
  nfloat4* outp = (nfloat4*)out;
  const int wlim = (NW - w0) < WT ? (NW - w0) : WT;
#pragma unroll
  for (int kk = 0; kk < 2; ++kk) {
    const int k = wv + kk * 4;
#pragma unroll 4
    for (int w = 0; w < wlim; ++w) {
      const int s = w + CIC * k;
      const int lb = slbl[s];                       // LDS broadcast
      const float4 e = e2b[lb * 64 + lane];         // L1/L2-hot (32 KB set)
      const float4 sv = S4[s * 64 + lane];
      nfloat4 o;
      o.x = e.x * sv.x; o.y = e.y * sv.y; o.z = e.z * sv.z; o.w = e.w * sv.w;
      __builtin_nontemporal_store(
          o, &outp[(((size_t)b * NW + w0 + w) * NK + k) * 64 + lane]);
    }
  }
}

extern "C" void kernel_launch(void* const* d_in, const int* in_sizes, int n_in,
                              void* d_out, int out_size, void* d_ws, size_t ws_size,
                              hipStream_t stream) {
  const float* vis   = (const float*)d_in[0];
  const float* query = (const float*)d_in[1];
  const float* W1    = (const float*)d_in[2];
  const float* b1    = (const float*)d_in[3];
  const float* W2    = (const float*)d_in[4];
  const float* b2    = (const float*)d_in[5];
  float* out = (float*)d_out;

  // Workspace: enc1 (64K f), enc2 (64K f) = 512 KB (labels no longer global)
  float* enc1 = (float*)d_ws;
  float* enc2 = enc1 + (size_t)B * L * C;

  enc_kernel<<<dim3(8, B, 4), 256, 0, stream>>>(query, W1, b1, W2, b2, enc1, enc2);
  fused_kernel<<<dim3((NW + WT - 1) / WT, B), 256, 0, stream>>>(vis, enc1, enc2, out);
}